// Round 7
// baseline (225.461 us; speedup 1.0000x reference)
//
#include <hip/hip_runtime.h>
#include <hip/hip_bf16.h>

namespace {

constexpr int SEQ = 2048;
constexpr int NB  = 2;
constexpr int DM  = 1024;
constexpr int NHD = 16;
constexpr int DKH = 64;
constexpr int MROWS = SEQ * NB;          // 4096
constexpr float SM_SCALE = 0.125f;       // 1/sqrt(64)
constexpr size_t HT = (size_t)NB * NHD * SEQ * DKH;   // per-tensor head-layout elems

typedef short bf16x8 __attribute__((ext_vector_type(8)));   // 8 bf16 = 4 VGPR
typedef short bf16x4 __attribute__((ext_vector_type(4)));   // 4 bf16 = 2 VGPR
typedef float f32x4  __attribute__((ext_vector_type(4)));

__device__ inline short f2bf(float f) {
    __hip_bfloat16 h = __float2bfloat16(f);
    return *reinterpret_cast<short*>(&h);
}

// Pack two f32 -> two bf16 (RTZ truncation) in ONE v_perm_b32.
// dst = [hi.b3 hi.b2 lo.b3 lo.b2]  => {bf16(lo), bf16(hi)} little-endian.
__device__ inline unsigned perm_pack_bf16(float hi, float lo) {
    return __builtin_amdgcn_perm(__float_as_uint(hi), __float_as_uint(lo),
                                 0x07060302u);
}

// async global->LDS, 16 B per lane. LDS dest = wave-uniform base + lane*16.
__device__ inline void gload_lds16(const short* g, short* l) {
    __builtin_amdgcn_global_load_lds(
        (const __attribute__((address_space(1))) void*)g,
        (__attribute__((address_space(3))) void*)l, 16, 0, 0);
}

__device__ inline f32x4 mfma16x16x16(bf16x4 a, bf16x4 b, f32x4 c) {
#if __has_builtin(__builtin_amdgcn_mfma_f32_16x16x16bf16_1k)
    return __builtin_amdgcn_mfma_f32_16x16x16bf16_1k(a, b, c, 0, 0, 0);
#else
    f32x4 d;
    asm("v_mfma_f32_16x16x16_bf16 %0, %1, %2, %3"
        : "=v"(d) : "v"(a), "v"(b), "v"(c));
    return d;
#endif
}

// ---------------------------------------------------------------------------
// fp32 -> bf16 casts.
__global__ __launch_bounds__(256)
void cast3_kernel(const float* __restrict__ q, const float* __restrict__ k,
                  const float* __restrict__ v, short* __restrict__ oq,
                  short* __restrict__ ok, short* __restrict__ ov)
{
    const int t = blockIdx.x * 256 + threadIdx.x;   // 8 floats / thread
    const float* s = blockIdx.y == 0 ? q : blockIdx.y == 1 ? k : v;
    short* d       = blockIdx.y == 0 ? oq : blockIdx.y == 1 ? ok : ov;
    const float4 a = ((const float4*)s)[2 * t];
    const float4 b = ((const float4*)s)[2 * t + 1];
    short r[8] = {f2bf(a.x), f2bf(a.y), f2bf(a.z), f2bf(a.w),
                  f2bf(b.x), f2bf(b.y), f2bf(b.z), f2bf(b.w)};
    *(bf16x8*)(d + 8 * (size_t)t) = *(bf16x8*)r;
}

__global__ __launch_bounds__(256)
void castW_kernel(const float* __restrict__ w0, const float* __restrict__ w1,
                  const float* __restrict__ w2, const float* __restrict__ w3,
                  short* __restrict__ o)
{
    const int t = blockIdx.x * 256 + threadIdx.x;
    const float* s = blockIdx.y == 0 ? w0 : blockIdx.y == 1 ? w1
                   : blockIdx.y == 2 ? w2 : w3;
    short* d = o + (size_t)blockIdx.y * (DM * DM);
    const float4 a = ((const float4*)s)[2 * t];
    const float4 b = ((const float4*)s)[2 * t + 1];
    short r[8] = {f2bf(a.x), f2bf(a.y), f2bf(a.z), f2bf(a.w),
                  f2bf(b.x), f2bf(b.y), f2bf(b.z), f2bf(b.w)};
    *(bf16x8*)(d + 8 * (size_t)t) = *(bf16x8*)r;
}

// ---------------------------------------------------------------------------
// Fused QKV MFMA GEMM: tile 128x128, BK=64, 4 waves.
// W rows are [wq;wk;wv] (N=3072); A-operand selected per block by segment.
// XCD swizzle: linear block id c (x fastest) round-robins XCDs (c&7 = XCD,
// verified via attn r6 FETCH drop). Remap so each XCD owns 4 m-tiles ->
// X tiles (3 MB) stay L2-resident; W streams once per XCD.
__global__ __launch_bounds__(256)
void gemm_qkv(const short* __restrict__ X0, const short* __restrict__ X1,
              const short* __restrict__ X2, const short* __restrict__ W,
              const float* __restrict__ b0, const float* __restrict__ b1,
              const float* __restrict__ b2, short* __restrict__ Yh)
{
    __shared__ short As[128 * 64];
    __shared__ short Bs[128 * 64];
    const int tid  = threadIdx.x;
    const int lane = tid & 63;
    const int wave = tid >> 6;
    const int i16  = lane & 15;
    const int quad = lane >> 4;

    const int c    = blockIdx.y * gridDim.x + blockIdx.x;  // 0..767
    const int xcd  = c & 7;
    const int idx  = c >> 3;                               // 0..95
    const int m0   = (xcd * 4 + (idx & 3)) * 128;
    const int n0g  = (idx >> 2) * 128;                     // 0..23 n-blocks

    const int R0   = (wave & 1) * 64;
    const int C0   = (wave >> 1) * 64;

    const int seg = n0g >> 10;
    const short* X = seg == 0 ? X0 : seg == 1 ? X1 : X2;

    const int srow = lane >> 3;               // 0..7
    const int ssl  = (lane & 7) ^ srow;       // logical slot for phys (lane&7)

    const short* ag[4]; short* al[4];
    const short* bg[4]; short* bl[4];
    #pragma unroll
    for (int i = 0; i < 4; ++i) {
        const int row = i * 32 + wave * 8 + srow;
        ag[i] = X + (size_t)(m0 + row) * DM + ssl * 8;
        al[i] = &As[i * 2048 + wave * 512];
        bg[i] = W + (size_t)(n0g + row) * DM + ssl * 8;
        bl[i] = &Bs[i * 2048 + wave * 512];
    }

    int aoff[4][2], boff[4][2];
    #pragma unroll
    for (int rt = 0; rt < 4; ++rt)
        #pragma unroll
        for (int kc = 0; kc < 2; ++kc)
            aoff[rt][kc] = (R0 + rt * 16 + i16) * 64 +
                           (((kc * 4 + quad) ^ (i16 & 7)) * 8);
    #pragma unroll
    for (int ct = 0; ct < 4; ++ct)
        #pragma unroll
        for (int kc = 0; kc < 2; ++kc)
            boff[ct][kc] = (C0 + ct * 16 + i16) * 64 +
                           (((kc * 4 + quad) ^ (i16 & 7)) * 8);

    f32x4 acc[4][4];
    #pragma unroll
    for (int rt = 0; rt < 4; ++rt)
        #pragma unroll
        for (int ct = 0; ct < 4; ++ct) acc[rt][ct] = (f32x4){0.f, 0.f, 0.f, 0.f};

    for (int ks = 0; ks < 16; ++ks) {
        __syncthreads();
        #pragma unroll
        for (int i = 0; i < 4; ++i) gload_lds16(ag[i], al[i]);
        #pragma unroll
        for (int i = 0; i < 4; ++i) gload_lds16(bg[i], bl[i]);
        __syncthreads();

        #pragma unroll
        for (int kc = 0; kc < 2; ++kc) {
            bf16x8 af[4], bfr[4];
            #pragma unroll
            for (int rt = 0; rt < 4; ++rt) af[rt] = *(const bf16x8*)&As[aoff[rt][kc]];
            #pragma unroll
            for (int ct = 0; ct < 4; ++ct) bfr[ct] = *(const bf16x8*)&Bs[boff[ct][kc]];
            #pragma unroll
            for (int rt = 0; rt < 4; ++rt)
                #pragma unroll
                for (int ct = 0; ct < 4; ++ct)
                    acc[rt][ct] = __builtin_amdgcn_mfma_f32_16x16x32_bf16(
                        af[rt], bfr[ct], acc[rt][ct], 0, 0, 0);
        }
        #pragma unroll
        for (int i = 0; i < 4; ++i) { ag[i] += 64; bg[i] += 64; }
    }

    #pragma unroll
    for (int ct = 0; ct < 4; ++ct) {
        const int n = n0g + C0 + ct * 16 + i16;
        const int nn  = n & 1023;
        const int h = nn >> 6, dk = nn & 63;
        const float* bp = seg == 0 ? b0 : seg == 1 ? b1 : b2;
        const float bb = bp[nn];
        const float sc = seg == 0 ? SM_SCALE : 1.0f;
        short* dst = Yh + (size_t)seg * HT;
        #pragma unroll
        for (int rt = 0; rt < 4; ++rt)
            #pragma unroll
            for (int r = 0; r < 4; ++r) {
                const int m = m0 + R0 + rt * 16 + quad * 4 + r;
                const int s = m >> 1, b = m & 1;
                dst[((size_t)(b * NHD + h) * SEQ + s) * DKH + dk] =
                    f2bf((acc[rt][ct][r] + bb) * sc);
            }
    }
}

// ---------------------------------------------------------------------------
// Output projection: tile 128(M) x 64(N), 512 blocks, XCD-swizzled
// (4 m-tiles per XCD -> 1 MB X L2-resident, 2 MB W streamed per XCD).
__global__ __launch_bounds__(256)
void gemm_out(const short* __restrict__ X, const short* __restrict__ W,
              const float* __restrict__ bias, float* __restrict__ Y)
{
    __shared__ short As[128 * 64];   // 16 KB
    __shared__ short Bs[64 * 64];    // 8 KB
    const int tid  = threadIdx.x;
    const int lane = tid & 63;
    const int wave = tid >> 6;
    const int i16  = lane & 15;
    const int quad = lane >> 4;

    const int c   = blockIdx.y * gridDim.x + blockIdx.x;  // 0..511
    const int xcd = c & 7;
    const int idx = c >> 3;                               // 0..63
    const int m0  = (xcd * 4 + (idx & 3)) * 128;
    const int n0  = (idx >> 2) * 64;                      // 0..15 n-blocks

    const int R0   = wave * 32;

    const int srow = lane >> 3;
    const int ssl  = (lane & 7) ^ srow;

    const short* ag[4]; short* al[4];
    const short* bg[2]; short* bl[2];
    #pragma unroll
    for (int i = 0; i < 4; ++i) {
        const int row = i * 32 + wave * 8 + srow;
        ag[i] = X + (size_t)(m0 + row) * DM + ssl * 8;
        al[i] = &As[i * 2048 + wave * 512];
    }
    #pragma unroll
    for (int i = 0; i < 2; ++i) {
        const int row = i * 32 + wave * 8 + srow;
        bg[i] = W + (size_t)(n0 + row) * DM + ssl * 8;
        bl[i] = &Bs[i * 2048 + wave * 512];
    }

    int aoff[2][2], boff[4][2];
    #pragma unroll
    for (int rt = 0; rt < 2; ++rt)
        #pragma unroll
        for (int kc = 0; kc < 2; ++kc)
            aoff[rt][kc] = (R0 + rt * 16 + i16) * 64 +
                           (((kc * 4 + quad) ^ (i16 & 7)) * 8);
    #pragma unroll
    for (int ct = 0; ct < 4; ++ct)
        #pragma unroll
        for (int kc = 0; kc < 2; ++kc)
            boff[ct][kc] = (ct * 16 + i16) * 64 +
                           (((kc * 4 + quad) ^ (i16 & 7)) * 8);

    f32x4 acc[2][4];
    #pragma unroll
    for (int rt = 0; rt < 2; ++rt)
        #pragma unroll
        for (int ct = 0; ct < 4; ++ct) acc[rt][ct] = (f32x4){0.f, 0.f, 0.f, 0.f};

    for (int ks = 0; ks < 16; ++ks) {
        __syncthreads();
        #pragma unroll
        for (int i = 0; i < 4; ++i) gload_lds16(ag[i], al[i]);
        #pragma unroll
        for (int i = 0; i < 2; ++i) gload_lds16(bg[i], bl[i]);
        __syncthreads();

        #pragma unroll
        for (int kc = 0; kc < 2; ++kc) {
            bf16x8 af[2], bfr[4];
            #pragma unroll
            for (int rt = 0; rt < 2; ++rt) af[rt] = *(const bf16x8*)&As[aoff[rt][kc]];
            #pragma unroll
            for (int ct = 0; ct < 4; ++ct) bfr[ct] = *(const bf16x8*)&Bs[boff[ct][kc]];
            #pragma unroll
            for (int rt = 0; rt < 2; ++rt)
                #pragma unroll
                for (int ct = 0; ct < 4; ++ct)
                    acc[rt][ct] = __builtin_amdgcn_mfma_f32_16x16x32_bf16(
                        af[rt], bfr[ct], acc[rt][ct], 0, 0, 0);
        }
        #pragma unroll
        for (int i = 0; i < 4; ++i) ag[i] += 64;
        #pragma unroll
        for (int i = 0; i < 2; ++i) bg[i] += 64;
    }

    #pragma unroll
    for (int ct = 0; ct < 4; ++ct) {
        const int n = n0 + ct * 16 + i16;
        const float bb = bias[n];
        #pragma unroll
        for (int rt = 0; rt < 2; ++rt)
            #pragma unroll
            for (int r = 0; r < 4; ++r) {
                const int m = m0 + R0 + rt * 16 + quad * 4 + r;
                Y[(size_t)m * DM + n] = acc[rt][ct][r] + bb;
            }
    }
}

// ---------------------------------------------------------------------------
// V transpose per head: Vt[bh][dk][s] <- V[bh][s][dk]  (bf16)
__global__ __launch_bounds__(256)
void transpose_v(const short* __restrict__ V, short* __restrict__ Vt)
{
    __shared__ alignas(16) short tile[64][72];
    const int tid = threadIdx.x;
    const int s0  = blockIdx.x * 64;
    const int bh  = blockIdx.y;
    const int row = tid >> 2;           // 0..63
    const int c0  = (tid & 3) * 16;     // 0,16,32,48

    const short* src = V + ((size_t)bh * SEQ + s0 + row) * DKH + c0;
    *(bf16x8*)&tile[row][c0]     = *(const bf16x8*)src;
    *(bf16x8*)&tile[row][c0 + 8] = *(const bf16x8*)(src + 8);
    __syncthreads();

    alignas(16) short vals[16];
    #pragma unroll
    for (int i = 0; i < 16; ++i) vals[i] = tile[c0 + i][row];
    short* dst = Vt + ((size_t)bh * DKH + row) * SEQ + s0 + c0;
    *(bf16x8*)dst       = *(bf16x8*)&vals[0];
    *(bf16x8*)(dst + 8) = *(bf16x8*)&vals[8];
}

// ---------------------------------------------------------------------------
// MFMA flash attention, split-j: 512 thr = 8 waves = two 4-wave groups, each
// group handles one HALF of the key range (unnormalized softmax => O and l
// are purely additive over j; partials combined in LDS at the end).
// P pack: f32->bf16 via v_perm RTZ truncation (1 inst / 2 values); the
// truncation bias on P largely cancels in O = sum(p v)/sum(p).
// XCD swizzle: 4 bh per XCD -> 2 MB K/V working set per XCD L2.
__global__ __launch_bounds__(512)
void attn_mfma3(const short* __restrict__ Qb, const short* __restrict__ Kb,
                const short* __restrict__ Vtb, short* __restrict__ Xa)
{
    __shared__ char smem[35328];
    // staging (union'd with combine buffers):
    //   Ks half h: smem + h*8192          (64x64 bf16)
    //   Vs half h: smem + 16384 + h*8192  (64x64 bf16)
    // combine: Of[128][68] f32 at smem+0 (34816 B), Ls[128] f32 at +34816.
    float* Of = (float*)smem;
    float* Ls = (float*)(smem + 34816);

    const int tid  = threadIdx.x;
    const int lane = tid & 63;
    const int wave = tid >> 6;        // 0..7
    const int half = wave >> 2;       // j-range half
    const int w4   = wave & 3;        // q-row group
    const int i16  = lane & 15;
    const int quad = lane >> 4;

    // XCD swizzle: consecutive block ids round-robin XCDs (id%8 = XCD).
    const int c   = blockIdx.y * gridDim.x + blockIdx.x;   // 0..511
    const int xcd = c & 7;
    const int idx = c >> 3;                                // 0..63
    const int bh  = xcd * 4 + (idx >> 4);
    const int r0  = (idx & 15) * 128;

    short* Ks = (short*)(smem + half * 8192);
    short* Vs = (short*)(smem + 16384 + half * 8192);

    bf16x8 qf[2][2];
    #pragma unroll
    for (int qt = 0; qt < 2; ++qt) {
        const short* qrow =
            Qb + ((size_t)bh * SEQ + r0 + w4 * 32 + qt * 16 + i16) * DKH;
        qf[qt][0] = *(const bf16x8*)(qrow + quad * 8);
        qf[qt][1] = *(const bf16x8*)(qrow + 32 + quad * 8);
    }

    f32x4 o[2][4];
    #pragma unroll
    for (int qt = 0; qt < 2; ++qt)
        #pragma unroll
        for (int dkt = 0; dkt < 4; ++dkt) o[qt][dkt] = (f32x4){0.f, 0.f, 0.f, 0.f};
    float lsum[2] = {0.f, 0.f};

    const int srow = lane >> 3;              // 0..7
    const int ssl  = (lane & 7) ^ srow;
    const short* kg[2]; short* kl[2];
    const short* vg[2]; short* vl[2];
    #pragma unroll
    for (int i = 0; i < 2; ++i) {
        const int row = i * 32 + w4 * 8 + srow;
        kg[i] = Kb  + (size_t)bh * SEQ * DKH +
                (size_t)(half * 1024 + row) * DKH + ssl * 8;
        kl[i] = &Ks[i * 2048 + w4 * 512];
        vg[i] = Vtb + (size_t)bh * DKH * SEQ + (size_t)row * SEQ +
                half * 1024 + ssl * 8;
        vl[i] = &Vs[i * 2048 + w4 * 512];
    }

    int koff[4][2];
    #pragma unroll
    for (int t = 0; t < 4; ++t)
        #pragma unroll
        for (int kc = 0; kc < 2; ++kc)
            koff[t][kc] = (t * 16 + i16) * 64 +
                          (((kc * 4 + quad) ^ (i16 & 7)) * 8);
    int voff[4][4];
    #pragma unroll
    for (int jw = 0; jw < 4; ++jw)
        #pragma unroll
        for (int dkt = 0; dkt < 4; ++dkt)
            voff[jw][dkt] = (dkt * 16 + i16) * 64 +
                            (((2 * jw + (quad >> 1)) ^ (i16 & 7)) * 8) +
                            (quad & 1) * 4;

    for (int jt = 0; jt < 16; ++jt) {
        __syncthreads();
        gload_lds16(kg[0] + (size_t)jt * 64 * DKH, kl[0]);
        gload_lds16(kg[1] + (size_t)jt * 64 * DKH, kl[1]);
        gload_lds16(vg[0] + jt * 64, vl[0]);
        gload_lds16(vg[1] + jt * 64, vl[1]);
        __syncthreads();

        bf16x8 kf[4][2];
        #pragma unroll
        for (int t = 0; t < 4; ++t) {
            kf[t][0] = *(const bf16x8*)&Ks[koff[t][0]];
            kf[t][1] = *(const bf16x8*)&Ks[koff[t][1]];
        }

        bf16x4 pa[2][4];
        #pragma unroll
        for (int qt = 0; qt < 2; ++qt) {
            #pragma unroll
            for (int t = 0; t < 4; ++t) {
                f32x4 st = (f32x4){0.f, 0.f, 0.f, 0.f};
                st = __builtin_amdgcn_mfma_f32_16x16x32_bf16(kf[t][0], qf[qt][0], st, 0, 0, 0);
                st = __builtin_amdgcn_mfma_f32_16x16x32_bf16(kf[t][1], qf[qt][1], st, 0, 0, 0);
                const float e0 = __expf(st[0]);
                const float e1 = __expf(st[1]);
                const float e2 = __expf(st[2]);
                const float e3 = __expf(st[3]);
                lsum[qt] += (e0 + e1) + (e2 + e3);
                union { unsigned u[2]; bf16x4 v; } pk;
                pk.u[0] = perm_pack_bf16(e1, e0);
                pk.u[1] = perm_pack_bf16(e3, e2);
                pa[qt][t] = pk.v;
            }
        }

        #pragma unroll
        for (int jw = 0; jw < 4; ++jw) {
            #pragma unroll
            for (int dkt = 0; dkt < 4; ++dkt) {
                const bf16x4 vb = *(const bf16x4*)&Vs[voff[jw][dkt]];
                o[0][dkt] = mfma16x16x16(pa[0][jw], vb, o[0][dkt]);
                o[1][dkt] = mfma16x16x16(pa[1][jw], vb, o[1][dkt]);
            }
        }
    }

    // ---- combine halves ----
    float lred[2];
    #pragma unroll
    for (int qt = 0; qt < 2; ++qt) {
        float v = lsum[qt];
        v += __shfl_xor(v, 16, 64);
        v += __shfl_xor(v, 32, 64);
        lred[qt] = v;
    }

    __syncthreads();   // all staging reads done; smem reusable as Of/Ls
    if (half == 1) {
        #pragma unroll
        for (int qt = 0; qt < 2; ++qt) {
            if (quad == 0) Ls[w4 * 32 + qt * 16 + i16] = lred[qt];
            #pragma unroll
            for (int r = 0; r < 4; ++r) {
                const int row = w4 * 32 + qt * 16 + quad * 4 + r;
                #pragma unroll
                for (int dkt = 0; dkt < 4; ++dkt)
                    Of[row * 68 + dkt * 16 + i16] = o[qt][dkt][r];
            }
        }
    }
    __syncthreads();
    if (half == 0) {
        const int b = bh / NHD;
        const int h = bh % NHD;
        float linv[2];
        #pragma unroll
        for (int qt = 0; qt < 2; ++qt)
            linv[qt] = 1.f / (lred[qt] + Ls[w4 * 32 + qt * 16 + i16]);
        #pragma unroll
        for (int qt = 0; qt < 2; ++qt) {
            #pragma unroll
            for (int r = 0; r < 4; ++r) {
                const float iv = __shfl(linv[qt], quad * 4 + r, 64);
                const int row = w4 * 32 + qt * 16 + quad * 4 + r;
                const int s = r0 + row;
                const int m = s * NB + b;
                short* op = Xa + (size_t)m * DM + h * DKH;
                #pragma unroll
                for (int dkt = 0; dkt < 4; ++dkt)
                    op[dkt * 16 + i16] =
                        f2bf((o[qt][dkt][r] + Of[row * 68 + dkt * 16 + i16]) * iv);
            }
        }
    }
}

} // anonymous namespace

extern "C" void kernel_launch(void* const* d_in, const int* in_sizes, int n_in,
                              void* d_out, int out_size, void* d_ws, size_t ws_size,
                              hipStream_t stream)
{
    const float* query = (const float*)d_in[0];
    const float* key_  = (const float*)d_in[1];
    const float* value = (const float*)d_in[2];
    const float* wq    = (const float*)d_in[3];
    const float* bq    = (const float*)d_in[4];
    const float* wk    = (const float*)d_in[5];
    const float* bk    = (const float*)d_in[6];
    const float* wv    = (const float*)d_in[7];
    const float* bv    = (const float*)d_in[8];
    const float* wo    = (const float*)d_in[9];
    const float* bo    = (const float*)d_in[10];
    float* out = (float*)d_out;

    // workspace (56 MB, lifetime-safe aliasing):
    //  0 Qb | 8 Kb | 16 Vb | 24 Xq/Vt | 32 Xk/Xa | 40 Xv | 48 Wb[4][DM^2]
    char* ws = (char*)d_ws;
    const size_t HB = HT * sizeof(short);     // 8 MB
    short* Qb = (short*)(ws);
    short* Kb = Qb + HT;
    short* Vb = Qb + 2 * HT;
    short* Xq = (short*)(ws + 3 * HB);
    short* Vt = Xq;                           // alias: Xq dead after QKV gemm
    short* Xk = (short*)(ws + 4 * HB);
    short* Xa = Xk;                           // alias: Xk dead after QKV gemm
    short* Xv = (short*)(ws + 5 * HB);
    short* Wb = (short*)(ws + 6 * HB);        // [wq;wk;wv;wo] bf16

    cast3_kernel<<<dim3(MROWS * DM / (8 * 256), 3), 256, 0, stream>>>(
        query, key_, value, Xq, Xk, Xv);
    castW_kernel<<<dim3(DM * DM / (8 * 256), 4), 256, 0, stream>>>(
        wq, wk, wv, wo, Wb);

    // fused QKV projection: N = 3072, grid 32x24 = 768 blocks (XCD-swizzled).
    gemm_qkv<<<dim3(MROWS / 128, 3 * DM / 128), 256, 0, stream>>>(
        Xq, Xk, Xv, Wb, bq, bk, bv, Qb);

    transpose_v<<<dim3(SEQ / 64, NB * NHD), 256, 0, stream>>>(Vb, Vt);

    // split-j attention: 512 blocks x 512 thr
    attn_mfma3<<<dim3(SEQ / 128, NB * NHD), 512, 0, stream>>>(Qb, Kb, Vt, Xa);

    // output projection: 128x64 tiles, grid 32x16 = 512 blocks (XCD-swizzled)
    gemm_out<<<dim3(MROWS / 128, DM / 64), 256, 0, stream>>>(
        Xa, Wb + 3 * (size_t)DM * DM, bo, out);
}

// Round 8
// 220.583 us; speedup vs baseline: 1.0221x; 1.0221x over previous
//
#include <hip/hip_runtime.h>
#include <hip/hip_bf16.h>

namespace {

constexpr int SEQ = 2048;
constexpr int NB  = 2;
constexpr int DM  = 1024;
constexpr int NHD = 16;
constexpr int DKH = 64;
constexpr int MROWS = SEQ * NB;          // 4096
constexpr float SM_SCALE = 0.125f;       // 1/sqrt(64)
constexpr size_t HT = (size_t)NB * NHD * SEQ * DKH;   // per-tensor head-layout elems

typedef short bf16x8 __attribute__((ext_vector_type(8)));   // 8 bf16 = 4 VGPR
typedef short bf16x4 __attribute__((ext_vector_type(4)));   // 4 bf16 = 2 VGPR
typedef float f32x4  __attribute__((ext_vector_type(4)));

__device__ inline short f2bf(float f) {
    __hip_bfloat16 h = __float2bfloat16(f);
    return *reinterpret_cast<short*>(&h);
}

// Pack two f32 -> two bf16 (RTZ truncation) in ONE v_perm_b32.
__device__ inline unsigned perm_pack_bf16(float hi, float lo) {
    return __builtin_amdgcn_perm(__float_as_uint(hi), __float_as_uint(lo),
                                 0x07060302u);
}

// async global->LDS, 16 B per lane. LDS dest = wave-uniform base + lane*16.
__device__ inline void gload_lds16(const short* g, short* l) {
    __builtin_amdgcn_global_load_lds(
        (const __attribute__((address_space(1))) void*)g,
        (__attribute__((address_space(3))) void*)l, 16, 0, 0);
}

__device__ inline f32x4 mfma16x16x16(bf16x4 a, bf16x4 b, f32x4 c) {
#if __has_builtin(__builtin_amdgcn_mfma_f32_16x16x16bf16_1k)
    return __builtin_amdgcn_mfma_f32_16x16x16bf16_1k(a, b, c, 0, 0, 0);
#else
    f32x4 d;
    asm("v_mfma_f32_16x16x16_bf16 %0, %1, %2, %3"
        : "=v"(d) : "v"(a), "v"(b), "v"(c));
    return d;
#endif
}

// ---------------------------------------------------------------------------
// fp32 -> bf16 cast, activations (y=0..2) + weights (y=3..6) in one launch.
__global__ __launch_bounds__(256)
void cast_all(const float* __restrict__ q, const float* __restrict__ k,
              const float* __restrict__ v, const float* __restrict__ w0,
              const float* __restrict__ w1, const float* __restrict__ w2,
              const float* __restrict__ w3, short* __restrict__ oq,
              short* __restrict__ ok, short* __restrict__ ov,
              short* __restrict__ ow)
{
    const int y = blockIdx.y;
    const float* s;
    short* d;
    if (y < 3) {
        s = y == 0 ? q : y == 1 ? k : v;
        d = y == 0 ? oq : y == 1 ? ok : ov;
    } else {
        if (blockIdx.x >= 512) return;   // weights: DM*DM/8/256 = 512 blocks
        s = y == 3 ? w0 : y == 4 ? w1 : y == 5 ? w2 : w3;
        d = ow + (size_t)(y - 3) * (DM * DM);
    }
    const size_t t = (size_t)blockIdx.x * 256 + threadIdx.x;   // 8 floats/thr
    const float4 a = ((const float4*)s)[2 * t];
    const float4 b = ((const float4*)s)[2 * t + 1];
    short r[8] = {f2bf(a.x), f2bf(a.y), f2bf(a.z), f2bf(a.w),
                  f2bf(b.x), f2bf(b.y), f2bf(b.z), f2bf(b.w)};
    *(bf16x8*)(d + 8 * t) = *(bf16x8*)r;
}

// ---------------------------------------------------------------------------
// Fused QKV MFMA GEMM: tile 128x128, BK=64, 4 waves, XCD-swizzled.
// W rows are [wq;wk;wv] (N=3072); A-operand selected per block by segment.
// seg0 -> Qb (per-head, *SM_SCALE), seg1 -> Kb (per-head),
// seg2 -> Vt DIRECTLY TRANSPOSED [bh][dk][s] (kills the transpose kernel).
__global__ __launch_bounds__(256)
void gemm_qkv(const short* __restrict__ X0, const short* __restrict__ X1,
              const short* __restrict__ X2, const short* __restrict__ W,
              const float* __restrict__ b0, const float* __restrict__ b1,
              const float* __restrict__ b2, short* __restrict__ Qb,
              short* __restrict__ Kb, short* __restrict__ Vt)
{
    __shared__ short As[128 * 64];
    __shared__ short Bs[128 * 64];
    const int tid  = threadIdx.x;
    const int lane = tid & 63;
    const int wave = tid >> 6;
    const int i16  = lane & 15;
    const int quad = lane >> 4;

    const int c    = blockIdx.y * gridDim.x + blockIdx.x;  // 0..767
    const int xcd  = c & 7;
    const int idx  = c >> 3;                               // 0..95
    const int m0   = (xcd * 4 + (idx & 3)) * 128;
    const int n0g  = (idx >> 2) * 128;

    const int R0   = (wave & 1) * 64;
    const int C0   = (wave >> 1) * 64;

    const int seg = n0g >> 10;
    const short* X = seg == 0 ? X0 : seg == 1 ? X1 : X2;

    const int srow = lane >> 3;               // 0..7
    const int ssl  = (lane & 7) ^ srow;       // logical slot for phys (lane&7)

    const short* ag[4]; short* al[4];
    const short* bg[4]; short* bl[4];
    #pragma unroll
    for (int i = 0; i < 4; ++i) {
        const int row = i * 32 + wave * 8 + srow;
        ag[i] = X + (size_t)(m0 + row) * DM + ssl * 8;
        al[i] = &As[i * 2048 + wave * 512];
        bg[i] = W + (size_t)(n0g + row) * DM + ssl * 8;
        bl[i] = &Bs[i * 2048 + wave * 512];
    }

    int aoff[4][2], boff[4][2];
    #pragma unroll
    for (int rt = 0; rt < 4; ++rt)
        #pragma unroll
        for (int kc = 0; kc < 2; ++kc)
            aoff[rt][kc] = (R0 + rt * 16 + i16) * 64 +
                           (((kc * 4 + quad) ^ (i16 & 7)) * 8);
    #pragma unroll
    for (int ct = 0; ct < 4; ++ct)
        #pragma unroll
        for (int kc = 0; kc < 2; ++kc)
            boff[ct][kc] = (C0 + ct * 16 + i16) * 64 +
                           (((kc * 4 + quad) ^ (i16 & 7)) * 8);

    f32x4 acc[4][4];
    #pragma unroll
    for (int rt = 0; rt < 4; ++rt)
        #pragma unroll
        for (int ct = 0; ct < 4; ++ct) acc[rt][ct] = (f32x4){0.f, 0.f, 0.f, 0.f};

    for (int ks = 0; ks < 16; ++ks) {
        __syncthreads();
        #pragma unroll
        for (int i = 0; i < 4; ++i) gload_lds16(ag[i], al[i]);
        #pragma unroll
        for (int i = 0; i < 4; ++i) gload_lds16(bg[i], bl[i]);
        __syncthreads();

        #pragma unroll
        for (int kc = 0; kc < 2; ++kc) {
            bf16x8 af[4], bfr[4];
            #pragma unroll
            for (int rt = 0; rt < 4; ++rt) af[rt] = *(const bf16x8*)&As[aoff[rt][kc]];
            #pragma unroll
            for (int ct = 0; ct < 4; ++ct) bfr[ct] = *(const bf16x8*)&Bs[boff[ct][kc]];
            #pragma unroll
            for (int rt = 0; rt < 4; ++rt)
                #pragma unroll
                for (int ct = 0; ct < 4; ++ct)
                    acc[rt][ct] = __builtin_amdgcn_mfma_f32_16x16x32_bf16(
                        af[rt], bfr[ct], acc[rt][ct], 0, 0, 0);
        }
        #pragma unroll
        for (int i = 0; i < 4; ++i) { ag[i] += 64; bg[i] += 64; }
    }

    #pragma unroll
    for (int ct = 0; ct < 4; ++ct) {
        const int n = n0g + C0 + ct * 16 + i16;
        const int nn  = n & 1023;
        const int h = nn >> 6, dk = nn & 63;
        const float* bp = seg == 0 ? b0 : seg == 1 ? b1 : b2;
        const float bb = bp[nn];
        const float sc = seg == 0 ? SM_SCALE : 1.0f;
        #pragma unroll
        for (int rt = 0; rt < 4; ++rt)
            #pragma unroll
            for (int r = 0; r < 4; ++r) {
                const int m = m0 + R0 + rt * 16 + quad * 4 + r;
                const int s = m >> 1, b = m & 1;
                const short val = f2bf((acc[rt][ct][r] + bb) * sc);
                if (seg == 2) {
                    Vt[(((size_t)(b * NHD + h) * DKH + dk) << 11) + s] = val;
                } else {
                    short* dst = seg == 0 ? Qb : Kb;
                    dst[((size_t)(b * NHD + h) * SEQ + s) * DKH + dk] = val;
                }
            }
    }
}

// ---------------------------------------------------------------------------
// Output projection: tile 128(M) x 64(N), XCD-swizzled, DOUBLE-BUFFERED
// staging (prefetch ks+1 before computing ks; one barrier per k-step).
__global__ __launch_bounds__(256)
void gemm_out(const short* __restrict__ X, const short* __restrict__ W,
              const float* __restrict__ bias, float* __restrict__ Y)
{
    __shared__ short sAB[2][12288];   // per buf: As[0..8191], Bs[8192..12287]
    const int tid  = threadIdx.x;
    const int lane = tid & 63;
    const int wave = tid >> 6;
    const int i16  = lane & 15;
    const int quad = lane >> 4;

    const int c   = blockIdx.y * gridDim.x + blockIdx.x;  // 0..511
    const int xcd = c & 7;
    const int idx = c >> 3;
    const int m0  = (xcd * 4 + (idx & 3)) * 128;
    const int n0  = (idx >> 2) * 64;

    const int R0   = wave * 32;

    const int srow = lane >> 3;
    const int ssl  = (lane & 7) ^ srow;

    const short* ag[4]; int alo[4];
    const short* bg[2]; int blo[2];
    #pragma unroll
    for (int i = 0; i < 4; ++i) {
        const int row = i * 32 + wave * 8 + srow;
        ag[i] = X + (size_t)(m0 + row) * DM + ssl * 8;
        alo[i] = i * 2048 + wave * 512;
    }
    #pragma unroll
    for (int i = 0; i < 2; ++i) {
        const int row = i * 32 + wave * 8 + srow;
        bg[i] = W + (size_t)(n0 + row) * DM + ssl * 8;
        blo[i] = 8192 + i * 2048 + wave * 512;
    }

    int aoff[2][2], boff[4][2];
    #pragma unroll
    for (int rt = 0; rt < 2; ++rt)
        #pragma unroll
        for (int kc = 0; kc < 2; ++kc)
            aoff[rt][kc] = (R0 + rt * 16 + i16) * 64 +
                           (((kc * 4 + quad) ^ (i16 & 7)) * 8);
    #pragma unroll
    for (int ct = 0; ct < 4; ++ct)
        #pragma unroll
        for (int kc = 0; kc < 2; ++kc)
            boff[ct][kc] = 8192 + (ct * 16 + i16) * 64 +
                           (((kc * 4 + quad) ^ (i16 & 7)) * 8);

    f32x4 acc[2][4];
    #pragma unroll
    for (int rt = 0; rt < 2; ++rt)
        #pragma unroll
        for (int ct = 0; ct < 4; ++ct) acc[rt][ct] = (f32x4){0.f, 0.f, 0.f, 0.f};

    // prologue: stage ks=0 into buf0
    #pragma unroll
    for (int i = 0; i < 4; ++i) gload_lds16(ag[i], &sAB[0][alo[i]]);
    #pragma unroll
    for (int i = 0; i < 2; ++i) gload_lds16(bg[i], &sAB[0][blo[i]]);
    #pragma unroll
    for (int i = 0; i < 4; ++i) ag[i] += 64;
    #pragma unroll
    for (int i = 0; i < 2; ++i) bg[i] += 64;
    __syncthreads();

    for (int ks = 0; ks < 16; ++ks) {
        const int p = ks & 1;
        if (ks < 15) {
            #pragma unroll
            for (int i = 0; i < 4; ++i) gload_lds16(ag[i], &sAB[1 - p][alo[i]]);
            #pragma unroll
            for (int i = 0; i < 2; ++i) gload_lds16(bg[i], &sAB[1 - p][blo[i]]);
            #pragma unroll
            for (int i = 0; i < 4; ++i) ag[i] += 64;
            #pragma unroll
            for (int i = 0; i < 2; ++i) bg[i] += 64;
        }
        const short* buf = sAB[p];
        #pragma unroll
        for (int kc = 0; kc < 2; ++kc) {
            bf16x8 af[2], bfr[4];
            #pragma unroll
            for (int rt = 0; rt < 2; ++rt) af[rt] = *(const bf16x8*)&buf[aoff[rt][kc]];
            #pragma unroll
            for (int ct = 0; ct < 4; ++ct) bfr[ct] = *(const bf16x8*)&buf[boff[ct][kc]];
            #pragma unroll
            for (int rt = 0; rt < 2; ++rt)
                #pragma unroll
                for (int ct = 0; ct < 4; ++ct)
                    acc[rt][ct] = __builtin_amdgcn_mfma_f32_16x16x32_bf16(
                        af[rt], bfr[ct], acc[rt][ct], 0, 0, 0);
        }
        __syncthreads();
    }

    #pragma unroll
    for (int ct = 0; ct < 4; ++ct) {
        const int n = n0 + ct * 16 + i16;
        const float bb = bias[n];
        #pragma unroll
        for (int rt = 0; rt < 2; ++rt)
            #pragma unroll
            for (int r = 0; r < 4; ++r) {
                const int m = m0 + R0 + rt * 16 + quad * 4 + r;
                Y[(size_t)m * DM + n] = acc[rt][ct][r] + bb;
            }
    }
}

// ---------------------------------------------------------------------------
// MFMA flash attention, split-j + DOUBLE-BUFFERED staging.
// 512 thr = 8 waves = two 4-wave groups; group = one half of the key range
// (unnormalized softmax => O, l additive over j; LDS combine at the end).
// Per jt: prefetch jt+1 into the other buffer, THEN compute on this one,
// THEN one barrier (its vmcnt(0) lands after ~2k cycles of compute).
// LDS: 2 bufs x (Ks 16KB + Vs 16KB) = 64 KB; grid is 2 blocks/CU anyway so
// the extra LDS costs no occupancy. Combine buffers alias buffer storage.
__global__ __launch_bounds__(512)
void attn_mfma4(const short* __restrict__ Qb, const short* __restrict__ Kb,
                const short* __restrict__ Vtb, short* __restrict__ Xa)
{
    __shared__ short sm[32768];   // 64 KB: buf b at b*16384 shorts
    float* Of = (float*)sm;                       // [128][68] f32
    float* Ls = (float*)((char*)sm + 34816);      // [128] f32

    const int tid  = threadIdx.x;
    const int lane = tid & 63;
    const int wave = tid >> 6;        // 0..7
    const int half = wave >> 2;       // j-range half
    const int w4   = wave & 3;        // q-row group
    const int i16  = lane & 15;
    const int quad = lane >> 4;

    const int c   = blockIdx.y * gridDim.x + blockIdx.x;   // 0..511
    const int xcd = c & 7;
    const int idx = c >> 3;
    const int bh  = xcd * 4 + (idx >> 4);
    const int r0  = (idx & 15) * 128;

    bf16x8 qf[2][2];
    #pragma unroll
    for (int qt = 0; qt < 2; ++qt) {
        const short* qrow =
            Qb + ((size_t)bh * SEQ + r0 + w4 * 32 + qt * 16 + i16) * DKH;
        qf[qt][0] = *(const bf16x8*)(qrow + quad * 8);
        qf[qt][1] = *(const bf16x8*)(qrow + 32 + quad * 8);
    }

    f32x4 o[2][4];
    #pragma unroll
    for (int qt = 0; qt < 2; ++qt)
        #pragma unroll
        for (int dkt = 0; dkt < 4; ++dkt) o[qt][dkt] = (f32x4){0.f, 0.f, 0.f, 0.f};
    float lsum[2] = {0.f, 0.f};

    // staging: within a buffer, Ks half at half*4096, Vs half at 8192+half*4096
    const int srow = lane >> 3;              // 0..7
    const int ssl  = (lane & 7) ^ srow;
    const short* kg[2]; const short* vg[2];
    int kls[2], vls[2];
    #pragma unroll
    for (int i = 0; i < 2; ++i) {
        const int row = i * 32 + w4 * 8 + srow;
        kg[i] = Kb  + (size_t)bh * SEQ * DKH +
                (size_t)(half * 1024 + row) * DKH + ssl * 8;
        kls[i] = half * 4096 + i * 2048 + w4 * 512;
        vg[i] = Vtb + (size_t)bh * DKH * SEQ + (size_t)row * SEQ +
                half * 1024 + ssl * 8;
        vls[i] = 8192 + half * 4096 + i * 2048 + w4 * 512;
    }

    int koff[4][2];
    #pragma unroll
    for (int t = 0; t < 4; ++t)
        #pragma unroll
        for (int kc = 0; kc < 2; ++kc)
            koff[t][kc] = half * 4096 + (t * 16 + i16) * 64 +
                          (((kc * 4 + quad) ^ (i16 & 7)) * 8);
    int voff[4][4];
    #pragma unroll
    for (int jw = 0; jw < 4; ++jw)
        #pragma unroll
        for (int dkt = 0; dkt < 4; ++dkt)
            voff[jw][dkt] = 8192 + half * 4096 + (dkt * 16 + i16) * 64 +
                            (((2 * jw + (quad >> 1)) ^ (i16 & 7)) * 8) +
                            (quad & 1) * 4;

    // prologue: stage jt=0 into buf0
    gload_lds16(kg[0], &sm[kls[0]]);
    gload_lds16(kg[1], &sm[kls[1]]);
    gload_lds16(vg[0], &sm[vls[0]]);
    gload_lds16(vg[1], &sm[vls[1]]);
    __syncthreads();

    for (int jt = 0; jt < 16; ++jt) {
        const int p = jt & 1;
        if (jt < 15) {
            const int bo = (1 - p) * 16384;
            gload_lds16(kg[0] + (size_t)(jt + 1) * 64 * DKH, &sm[bo + kls[0]]);
            gload_lds16(kg[1] + (size_t)(jt + 1) * 64 * DKH, &sm[bo + kls[1]]);
            gload_lds16(vg[0] + (jt + 1) * 64, &sm[bo + vls[0]]);
            gload_lds16(vg[1] + (jt + 1) * 64, &sm[bo + vls[1]]);
        }
        const short* buf = sm + p * 16384;

        bf16x8 kf[4][2];
        #pragma unroll
        for (int t = 0; t < 4; ++t) {
            kf[t][0] = *(const bf16x8*)&buf[koff[t][0]];
            kf[t][1] = *(const bf16x8*)&buf[koff[t][1]];
        }

        bf16x4 pa[2][4];
        #pragma unroll
        for (int qt = 0; qt < 2; ++qt) {
            #pragma unroll
            for (int t = 0; t < 4; ++t) {
                f32x4 st = (f32x4){0.f, 0.f, 0.f, 0.f};
                st = __builtin_amdgcn_mfma_f32_16x16x32_bf16(kf[t][0], qf[qt][0], st, 0, 0, 0);
                st = __builtin_amdgcn_mfma_f32_16x16x32_bf16(kf[t][1], qf[qt][1], st, 0, 0, 0);
                const float e0 = __expf(st[0]);
                const float e1 = __expf(st[1]);
                const float e2 = __expf(st[2]);
                const float e3 = __expf(st[3]);
                lsum[qt] += (e0 + e1) + (e2 + e3);
                union { unsigned u[2]; bf16x4 v; } pk;
                pk.u[0] = perm_pack_bf16(e1, e0);
                pk.u[1] = perm_pack_bf16(e3, e2);
                pa[qt][t] = pk.v;
            }
        }

        #pragma unroll
        for (int jw = 0; jw < 4; ++jw) {
            #pragma unroll
            for (int dkt = 0; dkt < 4; ++dkt) {
                const bf16x4 vb = *(const bf16x4*)&buf[voff[jw][dkt]];
                o[0][dkt] = mfma16x16x16(pa[0][jw], vb, o[0][dkt]);
                o[1][dkt] = mfma16x16x16(pa[1][jw], vb, o[1][dkt]);
            }
        }
        __syncthreads();   // waves done with buf p; prefetch (jt+1) drained
    }

    // ---- combine halves ----
    float lred[2];
    #pragma unroll
    for (int qt = 0; qt < 2; ++qt) {
        float v = lsum[qt];
        v += __shfl_xor(v, 16, 64);
        v += __shfl_xor(v, 32, 64);
        lred[qt] = v;
    }

    if (half == 1) {
        #pragma unroll
        for (int qt = 0; qt < 2; ++qt) {
            if (quad == 0) Ls[w4 * 32 + qt * 16 + i16] = lred[qt];
            #pragma unroll
            for (int r = 0; r < 4; ++r) {
                const int row = w4 * 32 + qt * 16 + quad * 4 + r;
                #pragma unroll
                for (int dkt = 0; dkt < 4; ++dkt)
                    Of[row * 68 + dkt * 16 + i16] = o[qt][dkt][r];
            }
        }
    }
    __syncthreads();
    if (half == 0) {
        const int b = bh / NHD;
        const int h = bh % NHD;
        float linv[2];
        #pragma unroll
        for (int qt = 0; qt < 2; ++qt)
            linv[qt] = 1.f / (lred[qt] + Ls[w4 * 32 + qt * 16 + i16]);
        #pragma unroll
        for (int qt = 0; qt < 2; ++qt) {
            #pragma unroll
            for (int r = 0; r < 4; ++r) {
                const float iv = __shfl(linv[qt], quad * 4 + r, 64);
                const int row = w4 * 32 + qt * 16 + quad * 4 + r;
                const int s = r0 + row;
                const int m = s * NB + b;
                short* op = Xa + (size_t)m * DM + h * DKH;
                #pragma unroll
                for (int dkt = 0; dkt < 4; ++dkt)
                    op[dkt * 16 + i16] =
                        f2bf((o[qt][dkt][r] + Of[row * 68 + dkt * 16 + i16]) * iv);
            }
        }
    }
}

} // anonymous namespace

extern "C" void kernel_launch(void* const* d_in, const int* in_sizes, int n_in,
                              void* d_out, int out_size, void* d_ws, size_t ws_size,
                              hipStream_t stream)
{
    const float* query = (const float*)d_in[0];
    const float* key_  = (const float*)d_in[1];
    const float* value = (const float*)d_in[2];
    const float* wq    = (const float*)d_in[3];
    const float* bq    = (const float*)d_in[4];
    const float* wk    = (const float*)d_in[5];
    const float* bk    = (const float*)d_in[6];
    const float* wv    = (const float*)d_in[7];
    const float* bv    = (const float*)d_in[8];
    const float* wo    = (const float*)d_in[9];
    const float* bo    = (const float*)d_in[10];
    float* out = (float*)d_out;

    // workspace (56 MB):
    //  0 Qb | 8 Kb | 16 Vt | 24 Xq/Xa | 32 Xk | 40 Xv | 48 Wb[4][DM^2]
    char* ws = (char*)d_ws;
    const size_t HB = HT * sizeof(short);     // 8 MB
    short* Qb = (short*)(ws);
    short* Kb = Qb + HT;
    short* Vt = Qb + 2 * HT;                  // [bh][dk][s], written by gemm_qkv
    short* Xq = (short*)(ws + 3 * HB);
    short* Xa = Xq;                           // alias: Xq dead after QKV gemm
    short* Xk = (short*)(ws + 4 * HB);
    short* Xv = (short*)(ws + 5 * HB);
    short* Wb = (short*)(ws + 6 * HB);        // [wq;wk;wv;wo] bf16

    cast_all<<<dim3(MROWS * DM / (8 * 256), 7), 256, 0, stream>>>(
        query, key_, value, wq, wk, wv, wo, Xq, Xk, Xv, Wb);

    // fused QKV projection (V written pre-transposed), grid 768, XCD-swizzled
    gemm_qkv<<<dim3(MROWS / 128, 3 * DM / 128), 256, 0, stream>>>(
        Xq, Xk, Xv, Wb, bq, bk, bv, Qb, Kb, Vt);

    // split-j double-buffered attention: 512 blocks x 512 thr
    attn_mfma4<<<dim3(SEQ / 128, NB * NHD), 512, 0, stream>>>(Qb, Kb, Vt, Xa);

    // output projection: double-buffered, grid 512, XCD-swizzled
    gemm_out<<<dim3(MROWS / 128, DM / 64), 256, 0, stream>>>(
        Xa, Wb + 3 * (size_t)DM * DM, bo, out);
}